// Round 11
// baseline (137.100 us; speedup 1.0000x reference)
//
#include <hip/hip_runtime.h>
#include <stdint.h>

// DVH global loss, MI355X.
// B=4 batches, N=2^21 voxels/batch, 500 bins over [0,75].
// loss = mean_{b,j} ( suffix_sum_{k>j}(hist_p[b]-hist_g[b])[k] / (maskcount_b+1e-6) )^2
// Only the DIFFERENCE histogram matters: d[i] = hist_p[i] - hist_g[i] (exact in ints).
//
// R1: device fence -> per-wave L2 writeback -> 201 us. Reverted.
// R2: fence-free last-block protocol, 512x1024, atomic drain -> 41.5 us kernel.
// R3: 4096x256 -> 117 us: drain atomics scale with writer count (REPS=1 then).
// R4: per-block partial stores -> 1 MB single-block merge tail. Reverted.
// R5: 8-replica drain -> neutral. R6/R7/R8: load-MLP forcing (3 ways) ->
//     provably owned issue order, time identical -> NOT latency-bound per wave.
// R9: probe round -> bounded delivery+compute but split ambiguous.
// R10: branchless inner loop -> +1.6 us, fully explained by 3x LDS bank
//     conflicts. Divergence theory dead; LDS atomics ~2-5 us total.
// LEDGER: max-of-pipes ~12 us, sum ~28 us, observed ~44 us. Model that fits
//     all data: per-BLOCK latency ~21 us x 2 resident slots/CU = 43.8 us.
//     Block-level TLP is the only untested axis (R3 probed it confounded by
//     the drain explosion; REPS now controls that).
// R11: 1024 x 512-thread blocks (4 blocks/CU), REPS=16 so per-replica-region
//     writers stay at 16 (same drain contention as R5). Branchy inner loop
//     (R10 regression reverted). Single-variable A/B on block granularity.

#define NBINS 500
#define NHIST 501          // searchsorted index c in [0,500]; c>=1 for d>=0
#define BATCH 4
#define NPB (1 << 21)      // elements per batch
#define VPB (NPB / 4)      // float4 per batch (524288)
#define THREADS 512
#define BPB 256            // blocks per batch
#define STRIDE (BPB * THREADS)                // 131072 float4s; VPB/STRIDE == 4
#define TOTAL_BLOCKS (BPB * BATCH)            // 1024
#define REPS 16            // replica histograms per batch (16 writers/region)

// workspace layout (int32):
//   replica hists : [(b*REPS + r)*512 + i], i<512, r<16, b<4   (32768 ints)
//   maskcount     : [32768 + b]
//   done ctr      : [32772]
#define HIST_INTS (BATCH * REPS * 512)
#define MC_OFF HIST_INTS
#define CTR_OFF (HIST_INTS + 4)
#define ZERO_INTS (HIST_INTS + 8)

__device__ __forceinline__ int bin_of(float d) {
    // c = # of fp32 bins k*STEP that are <= d  (jnp.linspace(0,75,500),
    // searchsorted side='right'); d >= 0 guaranteed. VERIFIED EXACT - do not touch.
    const float STEP = 75.0f / 499.0f;
    const float INV  = 499.0f / 75.0f;
    int k = (int)(d * INV);
    if (k > 499) k = 499;
    if ((float)k * STEP > d) --k;
    else if (k < 499 && (float)(k + 1) * STEP <= d) ++k;
    if ((float)k * STEP > d) --k;   // safety second pass (k>=0 since bins[0]=0<=d)
    return k + 1;                   // in [1,500]
}

// Inline-asm 16B load (R8-verified: equal perf to HIP loads, pins load shape).
__device__ __forceinline__ float4 ldx4(const float4* __restrict__ sbase,
                                       unsigned voff) {
    float4 r;
    asm volatile("global_load_dwordx4 %0, %1, %2"
                 : "=&v"(r)
                 : "v"(voff), "s"(sbase));
    return r;
}

#define WAITSB(n) do { \
    asm volatile("s_waitcnt vmcnt(" #n ")" ::: "memory"); \
    __builtin_amdgcn_sched_barrier(0); \
} while (0)

__global__ __launch_bounds__(THREADS) void dvh_fused_kernel(
        const float4* __restrict__ dp, const float4* __restrict__ dg,
        const float4* __restrict__ dm, int* __restrict__ ws,
        float* __restrict__ out) {
    __shared__ int shd[512];
    __shared__ unsigned int smc;
    __shared__ int lastflag;
    __shared__ int wtot[8];
    __shared__ float facc[8];

    const int b = blockIdx.y;
    const int t = threadIdx.x;
    if (t < 512) shd[t] = 0;
    if (t == 0) smc = 0u;
    __syncthreads();

    // byte offsets (u32): max (2^21)*16 = 32 MB, fits easily
    const unsigned e0 = (unsigned)(b * VPB + blockIdx.x * THREADS + t);
    const unsigned o0 = e0 * 16u;
    const unsigned o1 = o0 + (unsigned)STRIDE * 16u;
    const unsigned o2 = o1 + (unsigned)STRIDE * 16u;
    const unsigned o3 = o2 + (unsigned)STRIDE * 16u;

    float4 mA = ldx4(dm, o0); float4 pA = ldx4(dp, o0); float4 gA = ldx4(dg, o0);
    float4 mB = ldx4(dm, o1); float4 pB = ldx4(dp, o1); float4 gB = ldx4(dg, o1);
    float4 mC = ldx4(dm, o2); float4 pC = ldx4(dp, o2); float4 gC = ldx4(dg, o2);

    unsigned int myc = 0;
#define DO(mm, pp, gg) \
    if (mm != 0.0f) { atomicAdd(&shd[bin_of(pp)], 1); atomicAdd(&shd[bin_of(gg)], -1); ++myc; }
#define PROC(MM, PP, GG) \
    DO(MM.x, PP.x, GG.x) DO(MM.y, PP.y, GG.y) DO(MM.z, PP.z, GG.z) DO(MM.w, PP.w, GG.w)

    WAITSB(6);               // chunk A landed; B,C in flight
    PROC(mA, pA, gA)
    float4 mD = ldx4(dm, o3); float4 pD = ldx4(dp, o3); float4 gD = ldx4(dg, o3);
    WAITSB(6);               // chunk B landed; C,D in flight
    PROC(mB, pB, gB)
    WAITSB(3);               // chunk C landed; D in flight
    PROC(mC, pC, gC)
    WAITSB(0);               // chunk D landed
    PROC(mD, pD, gD)
#undef PROC
#undef DO

    if (myc) atomicAdd(&smc, myc);
    __syncthreads();

    // Drain into one of 16 replica histograms (writer count per region = 16,
    // identical contention to R5's verified-neutral config).
    {
        const int rep = blockIdx.x & (REPS - 1);
        int* dst = &ws[(b * REPS + rep) * 512];
        if (t < 512) {
            int v = shd[t];
            if (v) atomicAdd(&dst[t], v);
        }
    }
    if (t == 0 && smc) atomicAdd((unsigned int*)&ws[MC_OFF + b], smc);

    // ---- last-arriving-block protocol (fence-free; verified R2/R4/R5) ----
    asm volatile("s_waitcnt vmcnt(0)" ::: "memory");
    __syncthreads();
    if (t == 0) {
        unsigned int old = atomicAdd((unsigned int*)&ws[CTR_OFF], 1u);
        lastflag = (old == TOTAL_BLOCKS - 1) ? 1 : 0;
    }
    __syncthreads();
    if (!lastflag) return;

    // Last block (512 threads = 8 waves): merge 16 replicas per batch,
    // scan over 512 positions (t == bin index), suffix, square.
    const int lane = t & 63;
    const int w = t >> 6;          // wave 0..7
    float acc = 0.0f;

    for (int bb = 0; bb < BATCH; ++bb) {
        int s = 0;
        if (t < NHIST) {
            const int pb = (bb * REPS) * 512 + t;
            #pragma unroll
            for (int r = 0; r < REPS; ++r) {
                s += __hip_atomic_load(&ws[pb + r * 512],
                                       __ATOMIC_RELAXED, __HIP_MEMORY_SCOPE_AGENT);
            }
        }
        // inclusive scan across the 512 threads
        int v = s;
        #pragma unroll
        for (int off = 1; off < 64; off <<= 1) {
            int n = __shfl_up(v, off, 64);
            if (lane >= off) v += n;
        }
        if (lane == 63) wtot[w] = v;
        __syncthreads();
        int offset = 0, total = 0;
        #pragma unroll
        for (int i = 0; i < 8; ++i) {
            int x = wtot[i];
            total += x;
            if (i < w) offset += x;
        }
        const int prefix = v + offset;   // inclusive prefix over d[0..t]
        const unsigned int mc = __hip_atomic_load(
            (unsigned int*)&ws[MC_OFF + bb], __ATOMIC_RELAXED,
            __HIP_MEMORY_SCOPE_AGENT);
        const float denom = (float)mc + 1e-6f;
        if (t < NBINS) {
            // count_ge[j] diff = sum_{k>=j+1} d[k] = total - incl_prefix[j]
            const float diff = (float)(total - prefix) / denom;
            acc += diff * diff;
        }
        __syncthreads();   // before wtot reuse next batch
    }

    // block reduction of acc
    #pragma unroll
    for (int off = 32; off > 0; off >>= 1) acc += __shfl_down(acc, off, 64);
    if (lane == 0) facc[w] = acc;
    __syncthreads();
    if (t == 0) {
        float ssum = 0.0f;
        #pragma unroll
        for (int i = 0; i < 8; ++i) ssum += facc[i];
        out[0] = ssum * (1.0f / (BATCH * NBINS));
    }
}

extern "C" void kernel_launch(void* const* d_in, const int* in_sizes, int n_in,
                              void* d_out, int out_size, void* d_ws, size_t ws_size,
                              hipStream_t stream) {
    const float4* dp = (const float4*)d_in[0];   // d_pred
    const float4* dg = (const float4*)d_in[1];   // d_gt
    const float4* dm = (const float4*)d_in[2];   // mask
    int* ws = (int*)d_ws;

    hipMemsetAsync(ws, 0, ZERO_INTS * sizeof(int), stream);

    dim3 grid(BPB, BATCH);
    dvh_fused_kernel<<<grid, dim3(THREADS), 0, stream>>>(dp, dg, dm, ws, (float*)d_out);
}

// Round 13
// 131.341 us; speedup vs baseline: 1.0438x; 1.0438x over previous
//
#include <hip/hip_runtime.h>
#include <stdint.h>

// DVH global loss, MI355X.
// B=4 batches, N=2^21 voxels/batch, 500 bins over [0,75].
// loss = mean_{b,j} ( suffix_sum_{k>j}(hist_p[b]-hist_g[b])[k] / (maskcount_b+1e-6) )^2
// Only the DIFFERENCE histogram matters: d[i] = hist_p[i] - hist_g[i] (exact in ints).
//
// R1: device fence -> per-wave L2 writeback -> 201 us. Reverted.
// R2: fence-free last-block protocol, 512x1024, atomic drain -> 41.5 us kernel.
// R3: 4096x256 -> 117 us (drain scales with writers). R4: partial-store ->
//     single-block 1 MB merge tail. R5: 8-replica drain -> neutral.
// R6/R7/R8: load-MLP forcing x3 -> R8 provably owned issue order, time
//     IDENTICAL to serial -> not per-wave-latency-bound.
// R9: probe+fused = 60 us total, split ambiguous (40+20 or 18+42).
// R10: branchless -> +1.6 us == added bank-conflict cycles 1:1.
// R11: 4 blocks/CU -> worse. ALL structural axes null. Remaining axis:
//     CACHE STATE. Harness poison-fills 256 MB (dirtying L3) each iter;
//     our 49 MB of HBM misses each victimize a dirty line -> writeback
//     storm behind every miss -> effective ~2.4 TB/s.
// R12: nt loads; failed to compile (builtin rejects HIP_vector_type*).
// R13: same experiment, ext_vector_type(4) alias for the builtin.
//     Readout: faster = theory confirmed+captured; flat = internal floor
//     (declare next round); slower = delivery-sensitive via cache hits
//     (roofline-given-machine-state). FETCH_SIZE rising ~100 MB = nt took.

#define NBINS 500
#define NHIST 501          // searchsorted index c in [0,500]; c>=1 for d>=0
#define BATCH 4
#define NPB (1 << 21)      // elements per batch
#define VPB (NPB / 4)      // float4 per batch
#define THREADS 1024
#define BLOCKS_PER_BATCH 128
#define STRIDE (BLOCKS_PER_BATCH * THREADS)   // 131072 float4s; VPB/STRIDE == 4
#define TOTAL_BLOCKS (BLOCKS_PER_BATCH * BATCH)   // 512
#define REPS 8             // replica histograms per batch

// workspace layout (int32):
//   replica hists : [(b*REPS + r)*512 + i], i<512, r<8, b<4   (16384 ints)
//   maskcount     : [16384 + b]
//   done ctr      : [16388]
#define HIST_INTS (BATCH * REPS * 512)
#define MC_OFF HIST_INTS
#define CTR_OFF (HIST_INTS + 4)
#define ZERO_INTS (HIST_INTS + 8)

__device__ __forceinline__ int bin_of(float d) {
    // c = # of fp32 bins k*STEP that are <= d  (jnp.linspace(0,75,500),
    // searchsorted side='right'); d >= 0 guaranteed. VERIFIED EXACT - do not touch.
    const float STEP = 75.0f / 499.0f;
    const float INV  = 499.0f / 75.0f;
    int k = (int)(d * INV);
    if (k > 499) k = 499;
    if ((float)k * STEP > d) --k;
    else if (k < 499 && (float)(k + 1) * STEP <= d) ++k;
    if ((float)k * STEP > d) --k;   // safety second pass (k>=0 since bins[0]=0<=d)
    return k + 1;                   // in [1,500]
}

// Native clang vector type accepted by __builtin_nontemporal_load.
typedef float float4n __attribute__((ext_vector_type(4)));

// Non-temporal 16B load: no-allocate streaming read (emits nt-flagged
// global_load_dwordx4). Load sinking is irrelevant here (R8 null).
__device__ __forceinline__ float4 ldnt(const float4* __restrict__ p) {
    float4n v = __builtin_nontemporal_load((const float4n*)p);
    float4 r; r.x = v.x; r.y = v.y; r.z = v.z; r.w = v.w;
    return r;
}

__global__ __launch_bounds__(THREADS) void dvh_fused_kernel(
        const float4* __restrict__ dp, const float4* __restrict__ dg,
        const float4* __restrict__ dm, int* __restrict__ ws,
        float* __restrict__ out) {
    __shared__ int shd[512];
    __shared__ unsigned int smc;
    __shared__ int lastflag;
    __shared__ int wtot[2][8];
    __shared__ float facc[16];

    const int b = blockIdx.y;
    const int t = threadIdx.x;
    if (t < 512) shd[t] = 0;
    if (t == 0) smc = 0u;
    __syncthreads();

    const size_t base = (size_t)b * VPB + blockIdx.x * THREADS + t;
    float4 mA = ldnt(dm + base);              float4 pA = ldnt(dp + base);              float4 gA = ldnt(dg + base);
    float4 mB = ldnt(dm + base + STRIDE);     float4 pB = ldnt(dp + base + STRIDE);     float4 gB = ldnt(dg + base + STRIDE);
    float4 mC = ldnt(dm + base + 2 * STRIDE); float4 pC = ldnt(dp + base + 2 * STRIDE); float4 gC = ldnt(dg + base + 2 * STRIDE);
    float4 mD = ldnt(dm + base + 3 * STRIDE); float4 pD = ldnt(dp + base + 3 * STRIDE); float4 gD = ldnt(dg + base + 3 * STRIDE);

    unsigned int myc = 0;
#define DO(mm, pp, gg) \
    if (mm != 0.0f) { atomicAdd(&shd[bin_of(pp)], 1); atomicAdd(&shd[bin_of(gg)], -1); ++myc; }
#define PROC(MM, PP, GG) \
    DO(MM.x, PP.x, GG.x) DO(MM.y, PP.y, GG.y) DO(MM.z, PP.z, GG.z) DO(MM.w, PP.w, GG.w)
    PROC(mA, pA, gA)
    PROC(mB, pB, gB)
    PROC(mC, pC, gC)
    PROC(mD, pD, gD)
#undef PROC
#undef DO

    if (myc) atomicAdd(&smc, myc);
    __syncthreads();

    // Drain into one of 8 replica histograms (R5-verified neutral structure).
    {
        const int rep = blockIdx.x & (REPS - 1);
        int* dst = &ws[(b * REPS + rep) * 512];
        if (t < 512) {
            int v = shd[t];
            if (v) atomicAdd(&dst[t], v);
        }
    }
    if (t == 0 && smc) atomicAdd((unsigned int*)&ws[MC_OFF + b], smc);

    // ---- last-arriving-block protocol (fence-free; verified R2/R4/R5) ----
    asm volatile("s_waitcnt vmcnt(0)" ::: "memory");
    __syncthreads();
    if (t == 0) {
        unsigned int old = atomicAdd((unsigned int*)&ws[CTR_OFF], 1u);
        lastflag = (old == TOTAL_BLOCKS - 1) ? 1 : 0;
    }
    __syncthreads();
    if (!lastflag) return;

    // Last block: merge 8 replicas per batch (64 KB), scan, suffix, square.
    const int lane = t & 63;
    const int w = t >> 6;
    const int h = t >> 9;
    const int j = t & 511;
    const int wl = (t >> 6) & 7;
    float acc = 0.0f;

    #pragma unroll
    for (int bi = 0; bi < 2; ++bi) {
        const int bb = h * 2 + bi;
        int s = 0;
        const int pb = (bb * REPS) * 512 + j;
        #pragma unroll
        for (int r = 0; r < REPS; ++r) {
            s += __hip_atomic_load(&ws[pb + r * 512],
                                   __ATOMIC_RELAXED, __HIP_MEMORY_SCOPE_AGENT);
        }
        int v = s;
        #pragma unroll
        for (int off = 1; off < 64; off <<= 1) {
            int n = __shfl_up(v, off, 64);
            if (lane >= off) v += n;
        }
        if (lane == 63) wtot[h][wl] = v;
        __syncthreads();
        int offset = 0, total = 0;
        #pragma unroll
        for (int i = 0; i < 8; ++i) {
            int x = wtot[h][i];
            total += x;
            if (i < wl) offset += x;
        }
        const int prefix = v + offset;
        const unsigned int mc = __hip_atomic_load(
            (unsigned int*)&ws[MC_OFF + bb], __ATOMIC_RELAXED,
            __HIP_MEMORY_SCOPE_AGENT);
        const float denom = (float)mc + 1e-6f;
        if (j < NBINS) {
            const float diff = (float)(total - prefix) / denom;
            acc += diff * diff;
        }
        __syncthreads();
    }

    #pragma unroll
    for (int off = 32; off > 0; off >>= 1) acc += __shfl_down(acc, off, 64);
    if (lane == 0) facc[w] = acc;
    __syncthreads();
    if (t == 0) {
        float ssum = 0.0f;
        #pragma unroll
        for (int i = 0; i < 16; ++i) ssum += facc[i];
        out[0] = ssum * (1.0f / (BATCH * NBINS));
    }
}

extern "C" void kernel_launch(void* const* d_in, const int* in_sizes, int n_in,
                              void* d_out, int out_size, void* d_ws, size_t ws_size,
                              hipStream_t stream) {
    const float4* dp = (const float4*)d_in[0];   // d_pred
    const float4* dg = (const float4*)d_in[1];   // d_gt
    const float4* dm = (const float4*)d_in[2];   // mask
    int* ws = (int*)d_ws;

    hipMemsetAsync(ws, 0, ZERO_INTS * sizeof(int), stream);

    dim3 grid(BLOCKS_PER_BATCH, BATCH);
    dvh_fused_kernel<<<grid, dim3(THREADS), 0, stream>>>(dp, dg, dm, ws, (float*)d_out);
}

// Round 14
// 127.146 us; speedup vs baseline: 1.0783x; 1.0330x over previous
//
#include <hip/hip_runtime.h>
#include <stdint.h>

// DVH global loss, MI355X.
// B=4 batches, N=2^21 voxels/batch, 500 bins over [0,75].
// loss = mean_{b,j} ( suffix_sum_{k>j}(hist_p[b]-hist_g[b])[k] / (maskcount_b+1e-6) )^2
// Only the DIFFERENCE histogram matters: d[i] = hist_p[i] - hist_g[i] (exact in ints).
//
// FINAL STATE (R14) — best-measured configuration, session total 124.29 us:
//   512 x 1024-thread blocks, 12 loads/thread, LDS diff-histogram,
//   8-replica global drain, fence-free last-arriving-block reduce.
//
// Investigation ledger (14 rounds, all single-variable):
// R1: device fence -> per-wave L2 writeback storm -> 201 us. Fence-free instead.
// R2: fence-free last-block fusion -> 41.5 us kernel, neutral total.
// R3: 4096x256 blocks -> drain atomics scale with writers -> 117 us.
// R4: contention-free partial stores -> 1 MB single-block merge tail. Reverted.
// R5: 8-replica drain -> neutral (kept: harmless, bounds contention).
// R6: depth-3 load pipeline via sched_barrier -> 124.29 us total (best).
// R7: asm keep-alives -> compiler still serializes. Null.
// R8: full inline-asm counted-vmcnt pipeline, provably owned issue order ->
//     IDENTICAL to serial. Kernel is NOT per-wave-latency-bound.
// R9: delivery probe: probe+warm-fused ~60 us combined.
// R10: branchless inner loop -> +1.6 us == added LDS bank-conflict cycles 1:1.
// R11: 4 blocks/CU -> worse. R12/R13: non-temporal loads -> kernel slightly
//     faster, total slower (lost next-iter warm hits). Reverted.
// CONCLUSION: fused kernel ~41 us sits on the post-poison-fill delivery
// ceiling (~2.4-2.6 TB/s effective for this 3-stream pattern); timed window
// = ~82 us untouchable harness fills + ~41 us kernel + ~2 us memset.
// All structural axes probed null. This is the floor.

#define NBINS 500
#define NHIST 501          // searchsorted index c in [0,500]; c>=1 for d>=0
#define BATCH 4
#define NPB (1 << 21)      // elements per batch
#define VPB (NPB / 4)      // float4 per batch
#define THREADS 1024
#define BLOCKS_PER_BATCH 128
#define STRIDE (BLOCKS_PER_BATCH * THREADS)   // 131072 float4s; VPB/STRIDE == 4
#define TOTAL_BLOCKS (BLOCKS_PER_BATCH * BATCH)   // 512
#define REPS 8             // replica histograms per batch

// workspace layout (int32):
//   replica hists : [(b*REPS + r)*512 + i], i<512, r<8, b<4   (16384 ints)
//   maskcount     : [16384 + b]
//   done ctr      : [16388]
#define HIST_INTS (BATCH * REPS * 512)
#define MC_OFF HIST_INTS
#define CTR_OFF (HIST_INTS + 4)
#define ZERO_INTS (HIST_INTS + 8)

__device__ __forceinline__ int bin_of(float d) {
    // c = # of fp32 bins k*STEP that are <= d  (jnp.linspace(0,75,500),
    // searchsorted side='right'); d >= 0 guaranteed. VERIFIED EXACT - do not touch.
    const float STEP = 75.0f / 499.0f;
    const float INV  = 499.0f / 75.0f;
    int k = (int)(d * INV);
    if (k > 499) k = 499;
    if ((float)k * STEP > d) --k;
    else if (k < 499 && (float)(k + 1) * STEP <= d) ++k;
    if ((float)k * STEP > d) --k;   // safety second pass (k>=0 since bins[0]=0<=d)
    return k + 1;                   // in [1,500]
}

__global__ __launch_bounds__(THREADS) void dvh_fused_kernel(
        const float4* __restrict__ dp, const float4* __restrict__ dg,
        const float4* __restrict__ dm, int* __restrict__ ws,
        float* __restrict__ out) {
    __shared__ int shd[512];
    __shared__ unsigned int smc;
    __shared__ int lastflag;
    __shared__ int wtot[2][8];
    __shared__ float facc[16];

    const int b = blockIdx.y;
    const int t = threadIdx.x;
    if (t < 512) shd[t] = 0;
    if (t == 0) smc = 0u;
    __syncthreads();

    const size_t base = (size_t)b * VPB + blockIdx.x * THREADS + t;

    // depth-3 pipeline (R6 best-measured form)
    float4 mA = dm[base];              float4 pA = dp[base];              float4 gA = dg[base];
    float4 mB = dm[base + STRIDE];     float4 pB = dp[base + STRIDE];     float4 gB = dg[base + STRIDE];
    float4 mC = dm[base + 2 * STRIDE]; float4 pC = dp[base + 2 * STRIDE]; float4 gC = dg[base + 2 * STRIDE];
    __builtin_amdgcn_sched_barrier(0);

    unsigned int myc = 0;
#define DO(mm, pp, gg) \
    if (mm != 0.0f) { atomicAdd(&shd[bin_of(pp)], 1); atomicAdd(&shd[bin_of(gg)], -1); ++myc; }
#define PROC(MM, PP, GG) \
    DO(MM.x, PP.x, GG.x) DO(MM.y, PP.y, GG.y) DO(MM.z, PP.z, GG.z) DO(MM.w, PP.w, GG.w)

    PROC(mA, pA, gA)
    float4 mD = dm[base + 3 * STRIDE]; float4 pD = dp[base + 3 * STRIDE]; float4 gD = dg[base + 3 * STRIDE];
    __builtin_amdgcn_sched_barrier(0);
    PROC(mB, pB, gB)
    PROC(mC, pC, gC)
    PROC(mD, pD, gD)
#undef PROC
#undef DO

    if (myc) atomicAdd(&smc, myc);
    __syncthreads();

    // Drain into one of 8 replica histograms (R5-verified structure).
    {
        const int rep = blockIdx.x & (REPS - 1);
        int* dst = &ws[(b * REPS + rep) * 512];
        if (t < 512) {
            int v = shd[t];
            if (v) atomicAdd(&dst[t], v);
        }
    }
    if (t == 0 && smc) atomicAdd((unsigned int*)&ws[MC_OFF + b], smc);

    // ---- last-arriving-block protocol (fence-free; verified R2..R13) ----
    asm volatile("s_waitcnt vmcnt(0)" ::: "memory");
    __syncthreads();
    if (t == 0) {
        unsigned int old = atomicAdd((unsigned int*)&ws[CTR_OFF], 1u);
        lastflag = (old == TOTAL_BLOCKS - 1) ? 1 : 0;
    }
    __syncthreads();
    if (!lastflag) return;

    // Last block: merge 8 replicas per batch (64 KB), scan, suffix, square.
    const int lane = t & 63;
    const int w = t >> 6;
    const int h = t >> 9;
    const int j = t & 511;
    const int wl = (t >> 6) & 7;
    float acc = 0.0f;

    #pragma unroll
    for (int bi = 0; bi < 2; ++bi) {
        const int bb = h * 2 + bi;
        int s = 0;
        const int pb = (bb * REPS) * 512 + j;
        #pragma unroll
        for (int r = 0; r < REPS; ++r) {
            s += __hip_atomic_load(&ws[pb + r * 512],
                                   __ATOMIC_RELAXED, __HIP_MEMORY_SCOPE_AGENT);
        }
        int v = s;
        #pragma unroll
        for (int off = 1; off < 64; off <<= 1) {
            int n = __shfl_up(v, off, 64);
            if (lane >= off) v += n;
        }
        if (lane == 63) wtot[h][wl] = v;
        __syncthreads();
        int offset = 0, total = 0;
        #pragma unroll
        for (int i = 0; i < 8; ++i) {
            int x = wtot[h][i];
            total += x;
            if (i < wl) offset += x;
        }
        const int prefix = v + offset;
        const unsigned int mc = __hip_atomic_load(
            (unsigned int*)&ws[MC_OFF + bb], __ATOMIC_RELAXED,
            __HIP_MEMORY_SCOPE_AGENT);
        const float denom = (float)mc + 1e-6f;
        if (j < NBINS) {
            const float diff = (float)(total - prefix) / denom;
            acc += diff * diff;
        }
        __syncthreads();
    }

    #pragma unroll
    for (int off = 32; off > 0; off >>= 1) acc += __shfl_down(acc, off, 64);
    if (lane == 0) facc[w] = acc;
    __syncthreads();
    if (t == 0) {
        float ssum = 0.0f;
        #pragma unroll
        for (int i = 0; i < 16; ++i) ssum += facc[i];
        out[0] = ssum * (1.0f / (BATCH * NBINS));
    }
}

extern "C" void kernel_launch(void* const* d_in, const int* in_sizes, int n_in,
                              void* d_out, int out_size, void* d_ws, size_t ws_size,
                              hipStream_t stream) {
    const float4* dp = (const float4*)d_in[0];   // d_pred
    const float4* dg = (const float4*)d_in[1];   // d_gt
    const float4* dm = (const float4*)d_in[2];   // mask
    int* ws = (int*)d_ws;

    hipMemsetAsync(ws, 0, ZERO_INTS * sizeof(int), stream);

    dim3 grid(BLOCKS_PER_BATCH, BATCH);
    dvh_fused_kernel<<<grid, dim3(THREADS), 0, stream>>>(dp, dg, dm, ws, (float*)d_out);
}